// Round 1
// 811.550 us; speedup vs baseline: 1.0654x; 1.0654x over previous
//
#include <hip/hip_runtime.h>

#define DIM   33
#define DIM2  (DIM*DIM)        // 1089
#define DIM3  (DIM*DIM*DIM)    // 35937
#define HW    (1080*1920)      // 2,073,600 pixels per plane
#define NIMG  16
#define GPI   (HW/4)           // 518,400 float4 groups per plane
#define TOTAL_GROUPS (NIMG*GPI)  // 8,294,400

typedef _Float16 half8 __attribute__((ext_vector_type(8)));
typedef float    f4    __attribute__((ext_vector_type(4)));

__device__ __forceinline__ float lerpf(float a, float b, float t) {
    return fmaf(t, b - a, a);
}

// ---------------------------------------------------------------------------
// Build packed LUT: for each cell (b,g,r) store 8 corners x 3 channels as fp16
// in one 64B-aligned 64B cell (48B data + 16B pad).
// layout: h[((db*2+dg)*2+dr)*3 + c]
// ---------------------------------------------------------------------------
__global__ void build_lut_kernel(const float* __restrict__ lut,
                                 half8* __restrict__ ws) {
    int cell = blockIdx.x * blockDim.x + threadIdx.x;
    if (cell >= DIM3) return;
    int b   = cell / DIM2;
    int rem = cell - b * DIM2;
    int g   = rem / DIM;
    int r   = rem - g * DIM;
    int bs[2] = { b, min(b + 1, DIM - 1) };
    int gs[2] = { g, min(g + 1, DIM - 1) };
    int rs[2] = { r, min(r + 1, DIM - 1) };

    _Float16 h[32];
#pragma unroll
    for (int i = 24; i < 32; ++i) h[i] = (_Float16)0.0f;
#pragma unroll
    for (int db = 0; db < 2; ++db)
#pragma unroll
        for (int dg = 0; dg < 2; ++dg)
#pragma unroll
            for (int dr = 0; dr < 2; ++dr) {
                int base = bs[db] * DIM2 + gs[dg] * DIM + rs[dr];
#pragma unroll
                for (int c = 0; c < 3; ++c)
                    h[((db * 2 + dg) * 2 + dr) * 3 + c] =
                        (_Float16)lut[c * DIM3 + base];
            }

    half8* dst = ws + (size_t)cell * 4;
#pragma unroll
    for (int q = 0; q < 4; ++q) {
        half8 v;
#pragma unroll
        for (int i = 0; i < 8; ++i) v[i] = h[q * 8 + i];
        dst[q] = v;
    }
}

// ---------------------------------------------------------------------------
// Main kernel: 4 pixels per thread. Restructured for memory-level parallelism:
//   phase 1: compute all 4 cell addresses + fracs
//   phase 2: issue ALL 12 table gathers (sched_barrier pins them above use)
//   phase 3: convert + lerp + store
// Rationale: previous version kept only ~3 gathers in flight per wave
// (Little's law from counters: 0.48 lane-req/cy * ~200cy L2 latency / 32
// waves ~= 3). Batching 12 loads doubles per-CU outstanding requests even
// at the halved occupancy (VGPR ~100-128, 4 waves/SIMD).
// ---------------------------------------------------------------------------
__global__ __launch_bounds__(256, 4) void lut3d_kernel(
        const float* __restrict__ x,
        const half8* __restrict__ tab,
        float* __restrict__ out) {
    int tid = blockIdx.x * blockDim.x + threadIdx.x;
    if (tid >= TOTAL_GROUPS) return;

    const float kInvBin = (float)(32.0 / 1.000001);

    int n = tid / GPI;
    int j = tid - n * GPI;

    const f4* xin = (const f4*)(x + (size_t)n * 3 * HW) + j;
    f4 r4 = __builtin_nontemporal_load(xin);
    f4 g4 = __builtin_nontemporal_load(xin + GPI);
    f4 b4 = __builtin_nontemporal_load(xin + 2 * GPI);

    // ---- phase 1: addresses + fractional weights for all 4 pixels ----
    float dr[4], dg[4], dbw[4];
    const half8* pp[4];
#pragma unroll
    for (int e = 0; e < 4; ++e) {
        float tr = r4[e] * kInvBin;
        float tg = g4[e] * kInvBin;
        float tb = b4[e] * kInvBin;
        float flr = floorf(tr), flg = floorf(tg), flb = floorf(tb);
        dr[e]  = tr - flr;
        dg[e]  = tg - flg;
        dbw[e] = tb - flb;
        int ir = min(max((int)flr, 0), DIM - 2);
        int ig = min(max((int)flg, 0), DIM - 2);
        int ib = min(max((int)flb, 0), DIM - 2);
        int cell = (ib * DIM + ig) * DIM + ir;
        pp[e] = tab + (size_t)cell * 4;
    }

    // ---- phase 2: issue all 12 gathers back-to-back ----
    half8 q[4][3];
#pragma unroll
    for (int e = 0; e < 4; ++e) {
        q[e][0] = pp[e][0];
        q[e][1] = pp[e][1];
        q[e][2] = pp[e][2];
    }
    // Keep every gather issued before any consumption is scheduled.
    __builtin_amdgcn_sched_barrier(0);

    // ---- phase 3: convert + trilinear lerp (consume in load order) ----
    f4 o0, o1, o2;
#pragma unroll
    for (int e = 0; e < 4; ++e) {
        float v[24];
#pragma unroll
        for (int i = 0; i < 8; ++i) {
            v[i]      = (float)q[e][0][i];
            v[8 + i]  = (float)q[e][1][i];
            v[16 + i] = (float)q[e][2][i];
        }

        float res[3];
#pragma unroll
        for (int c = 0; c < 3; ++c) {
            float a00 = lerpf(v[c],      v[3 + c],  dr[e]);   // (b0,g0)
            float a01 = lerpf(v[6 + c],  v[9 + c],  dr[e]);   // (b0,g1)
            float a10 = lerpf(v[12 + c], v[15 + c], dr[e]);   // (b1,g0)
            float a11 = lerpf(v[18 + c], v[21 + c], dr[e]);   // (b1,g1)
            float c0  = lerpf(a00, a01, dg[e]);
            float c1  = lerpf(a10, a11, dg[e]);
            res[c]    = lerpf(c0, c1, dbw[e]);
        }
        o0[e] = res[0];
        o1[e] = res[1];
        o2[e] = res[2];
    }

    f4* op = (f4*)(out + (size_t)n * 3 * HW) + j;
    __builtin_nontemporal_store(o0, op);
    __builtin_nontemporal_store(o1, op + GPI);
    __builtin_nontemporal_store(o2, op + 2 * GPI);
}

// ---------------------------------------------------------------------------
// Fallback (only if ws too small): direct fp32 gathers, one pixel per thread.
// ---------------------------------------------------------------------------
__global__ void lut3d_fallback_kernel(const float* __restrict__ x,
                                      const float* __restrict__ lut,
                                      float* __restrict__ out) {
    long long tid = (long long)blockIdx.x * blockDim.x + threadIdx.x;
    if (tid >= (long long)NIMG * HW) return;
    const float kInvBin = (float)(32.0 / 1.000001);
    int n = (int)(tid / HW);
    int p = (int)(tid - (long long)n * HW);
    const float* xb = x + (size_t)n * 3 * HW;
    float r = xb[p], g = xb[HW + p], b = xb[2 * HW + p];
    float tr = r * kInvBin, tg = g * kInvBin, tb = b * kInvBin;
    float flr = floorf(tr), flg = floorf(tg), flb = floorf(tb);
    float dr = tr - flr, dg = tg - flg, db = tb - flb;
    int ir = min(max((int)flr, 0), DIM - 2);
    int ig = min(max((int)flg, 0), DIM - 2);
    int ib = min(max((int)flb, 0), DIM - 2);
    float* ob = out + (size_t)n * 3 * HW;
#pragma unroll
    for (int c = 0; c < 3; ++c) {
        const float* L = lut + (size_t)c * DIM3;
        int base = ib * DIM2 + ig * DIM + ir;
        float v000 = L[base],               v100 = L[base + 1];
        float v010 = L[base + DIM],         v110 = L[base + DIM + 1];
        float v001 = L[base + DIM2],        v101 = L[base + DIM2 + 1];
        float v011 = L[base + DIM2 + DIM],  v111 = L[base + DIM2 + DIM + 1];
        float a00 = lerpf(v000, v100, dr);
        float a01 = lerpf(v010, v110, dr);
        float a10 = lerpf(v001, v101, dr);
        float a11 = lerpf(v011, v111, dr);
        float c0 = lerpf(a00, a01, dg);
        float c1 = lerpf(a10, a11, dg);
        ob[(size_t)c * HW + p] = lerpf(c0, c1, db);
    }
}

extern "C" void kernel_launch(void* const* d_in, const int* in_sizes, int n_in,
                              void* d_out, int out_size, void* d_ws, size_t ws_size,
                              hipStream_t stream) {
    const float* lut = (const float*)d_in[0];
    const float* x   = (const float*)d_in[1];
    float*       out = (float*)d_out;

    const size_t ws_needed = (size_t)DIM3 * 64;
    if (ws_size >= ws_needed) {
        hipLaunchKernelGGL(build_lut_kernel,
                           dim3((DIM3 + 255) / 256), dim3(256), 0, stream,
                           lut, (half8*)d_ws);
        hipLaunchKernelGGL(lut3d_kernel,
                           dim3(TOTAL_GROUPS / 256), dim3(256), 0, stream,
                           x, (const half8*)d_ws, out);
    } else {
        long long total = (long long)NIMG * HW;
        hipLaunchKernelGGL(lut3d_fallback_kernel,
                           dim3((unsigned)((total + 255) / 256)), dim3(256), 0, stream,
                           x, lut, out);
    }
}